// Round 3
// baseline (1464.582 us; speedup 1.0000x reference)
//
#include <hip/hip_runtime.h>
#include <math.h>

typedef _Float16 f16;
typedef _Float16 f16x8 __attribute__((ext_vector_type(8)));
typedef _Float16 f16x4 __attribute__((ext_vector_type(4)));
typedef float f32x4 __attribute__((ext_vector_type(4)));

#define TT 1024
#define HH 128
#define SROW 272   // halves/row: 136 dwords -> bank shift 8/row; 16 bcast addrs = 2 per bank group (free)
#define NEV 24

__device__ __forceinline__ float sigm(float x){ return 1.f/(1.f + __expf(-x)); }
__device__ __forceinline__ float tanh_f(float x){
    float ax = fabsf(x);
    float e = __expf(-2.f*ax);
    float r = (1.f - e)/(1.f + e);
    return (x < 0.f) ? -r : r;
}

#define MF(a,b,c) __builtin_amdgcn_mfma_f32_16x16x32_f16((a),(b),(c),0,0,0)

// ---------------- prep: pack LSTM weights (f16, K=256) + gps cols (f32) + bias sum + fsim W^T ----------------
__global__ void pack_kernel(const float* __restrict__ W_ih, const float* __restrict__ W_hh,
                            const float* __restrict__ b_ih, const float* __restrict__ b_hh,
                            const float* __restrict__ Wi, const float* __restrict__ Wc, const float* __restrict__ Wo,
                            f16* __restrict__ Wpack, float* __restrict__ Wg, float* __restrict__ bsum,
                            float* __restrict__ WT)
{
    int idx = blockIdx.x*256 + threadIdx.x;
    if (idx < 512*256){
        int j = idx >> 8, k = idx & 255;
        float v = (k < 128) ? W_ih[j*130 + k] : W_hh[j*128 + (k-128)];
        Wpack[idx] = (f16)v;
    }
    if (idx < 1024){
        int j = idx >> 1, c = idx & 1;
        Wg[idx] = W_ih[j*130 + 128 + c];
    }
    if (idx < 512) bsum[idx] = b_ih[idx] + b_hh[idx];
    if (idx < 3*128*128){
        int w = idx >> 14, rem = idx & 16383, k = rem >> 7, u = rem & 127;
        const float* W = (w==0) ? Wi : (w==1) ? Wc : Wo;
        WT[idx] = W[u*128 + k];   // WT[w][k][u] = W[u][k]
    }
}

// ---------------- prep: length sort + per-stream sorted event lists ----------------
__device__ __forceinline__ void add_ev(int* et, int* es, int& n, int t, int slot, int len){
    if (t < 0 || t >= len) return;
    int p = n++;
    while (p > 0 && et[p-1] > t){ et[p] = et[p-1]; es[p] = es[p-1]; --p; }
    et[p] = t; es[p] = slot;
}

__global__ void sched_kernel(const int* __restrict__ len_t, const int* __restrict__ len_a, const int* __restrict__ len_f,
                             const int* __restrict__ sub_ta, const int* __restrict__ sub_tf,
                             const int* __restrict__ sub_a, const int* __restrict__ sub_f,
                             int* __restrict__ order, int* __restrict__ slen,
                             int* __restrict__ ev_t, int* __restrict__ ev_slot, int* __restrict__ nev)
{
    __shared__ int L[768];
    int s = threadIdx.x;              // 0..767, stream id = e*256 + b
    int e = s >> 8, b = s & 255;
    int len = (e==0) ? len_t[b] : (e==1) ? len_a[b] : len_f[b];
    L[s] = len;
    __syncthreads();
    int rank = 0;
    for (int i = 0; i < 768; ++i){
        int li = L[i];
        rank += (li > len) || (li == len && i < s);
    }
    order[rank] = s;                  // descending by length, bijective
    slen[s] = len;

    int et[NEV], es[NEV]; int n = 0;
    if (e == 0){
        for (int r = 0; r < 10; ++r){
            add_ev(et, es, n, sub_ta[b*10+r]-1, b*10+r,        len);
            add_ev(et, es, n, sub_tf[b*10+r]-1, 2560 + b*10+r, len);
        }
    } else if (e == 1){
        for (int r = 0; r < 10; ++r) add_ev(et, es, n, sub_a[b*10+r]-1, 5120 + b*10+r, len);
    } else {
        for (int r = 0; r < 10; ++r) add_ev(et, es, n, sub_f[b*10+r]-1, 7680 + b*10+r, len);
    }
    add_ev(et, es, n, len-1, 10240 + s, len);   // final hidden state
    nev[s] = n;
    for (int i = 0; i < n; ++i){ ev_t[s*NEV+i] = et[i]; ev_slot[s*NEV+i] = es[i]; }
}

// ---------------- main LSTM: 3 streams/block, K=256 MFMA + fp32 gps fold, 1 lgkm-only barrier/step ----------------
__launch_bounds__(512, 2)
__global__ void lstm_kernel(const float* __restrict__ gps0, const float* __restrict__ gps1, const float* __restrict__ gps2,
                            const int* __restrict__ grid0, const int* __restrict__ grid1, const int* __restrict__ grid2,
                            const float* __restrict__ E,
                            const f16* __restrict__ Wpack, const float* __restrict__ Wg, const float* __restrict__ bsum,
                            const int* __restrict__ order, const int* __restrict__ slen,
                            const int* __restrict__ ev_t, const int* __restrict__ ev_slot, const int* __restrict__ nev,
                            float* __restrict__ stash)
{
    __shared__ f16   A_s[2][4][SROW];   // double-buffered; phys rows 0..2 = streams; k<128 = x_emb, k in [128,256) = h
    __shared__ float gpb[2][3][2];      // double-buffered gps pair per stream (fp32)
    __shared__ int   ring_s[3][8];      // grid-index ring
    __shared__ int   ev_t_s[3][NEV];
    __shared__ int   ev_sl_s[3][NEV];

    const int tid  = threadIdx.x;
    const int lane = tid & 63;
    const int wv   = tid >> 6;
    const int q    = lane >> 4;         // 0..2 = nonlin stream q, 3 = staging
    const int li   = lane & 15;
    const int u    = (wv << 4) + li;    // unit 0..127
    const int qc   = (q < 3) ? q : 2;
    const int bi   = blockIdx.x;

    const f32x4* __restrict__ E4 = (const f32x4*)E;

    const int s0 = order[bi], s1 = order[bi+256], s2 = order[bi+512];
    const int l0 = slen[s0], l1 = slen[s1], l2 = slen[s2];
    int maxlen = l0 > l1 ? l0 : l1; if (l2 > maxlen) maxlen = l2;

    // ---- init LDS ----
    for (int i = tid; i < 2*4*SROW; i += 512) (&A_s[0][0][0])[i] = (f16)0.f;
    if (tid < 72){
        int m = tid / NEV, i = tid % NEV;
        int sm = (m==0) ? s0 : (m==1) ? s1 : s2;
        ev_t_s[m][i]  = ev_t[sm*NEV + i];
        ev_sl_s[m][i] = ev_slot[sm*NEV + i];
    }

    // ---- resident weight fragments ----
    f16x8 wI[8], wF[8], wG[8], wO[8];
    {
        const int kg = q << 3;
        #pragma unroll
        for (int ks = 0; ks < 8; ++ks){
            const int koff = ks*32 + kg;
            wI[ks] = *reinterpret_cast<const f16x8*>(Wpack + (size_t)(  0 + u) * 256 + koff);
            wF[ks] = *reinterpret_cast<const f16x8*>(Wpack + (size_t)(128 + u) * 256 + koff);
            wG[ks] = *reinterpret_cast<const f16x8*>(Wpack + (size_t)(256 + u) * 256 + koff);
            wO[ks] = *reinterpret_cast<const f16x8*>(Wpack + (size_t)(384 + u) * 256 + koff);
        }
    }
    // gps fold weights + biases (fp32)
    const float wgi0 = Wg[u*2],        wgi1 = Wg[u*2+1];
    const float wgf0 = Wg[(128+u)*2],  wgf1 = Wg[(128+u)*2+1];
    const float wgg0 = Wg[(256+u)*2],  wgg1 = Wg[(256+u)*2+1];
    const float wgo0 = Wg[(384+u)*2],  wgo1 = Wg[(384+u)*2+1];
    const float bI_r = bsum[u], bF_r = bsum[128+u], bG_r = bsum[256+u], bO_r = bsum[384+u];

    // ---- per-role state ----
    float creg = 0.f, hreg = 0.f;
    int len_q = 0, nev_q = 0, evp = 0, next_t = 1<<30;
    if (q < 3){
        int sq = (q==0)?s0:(q==1)?s1:s2;
        len_q = (q==0)?l0:(q==1)?l1:l2;
        nev_q = nev[sq];
    }

    // staging-lane state
    const int em   = li >> 2;                       // stream for E lanes (li<12)
    const int xoff = (wv << 4) + ((li & 3) << 2);   // unit offset of this lane's float4
    f32x4 ev_cur = {0.f,0.f,0.f,0.f};
    float gp_cur = 0.f;
    int   gd_cur = 0;
    const float* gps_p = nullptr;
    const int*   grid_p = nullptr;

    __syncthreads();   // LDS init + ev lists visible

    // ---- prologue ----
    if (q == 3){
        if (li < 12){
            int sm = (em==0)?s0:(em==1)?s1:s2;
            const int* gm = ((sm>>8)==0 ? grid0 : (sm>>8)==1 ? grid1 : grid2) + (size_t)(sm&255)*TT;
            int i0 = gm[0], i1 = gm[1];
            f32x4 x0 = {0.f,0.f,0.f,0.f};
            if (i0 != 0) x0 = E4[(size_t)i0*32 + (wv<<2) + (li&3)];
            f16x4 xd; xd[0]=(f16)x0[0]; xd[1]=(f16)x0[1]; xd[2]=(f16)x0[2]; xd[3]=(f16)x0[3];
            *reinterpret_cast<f16x4*>(&A_s[0][em][xoff]) = xd;
            if (i1 != 0) ev_cur = E4[(size_t)i1*32 + (wv<<2) + (li&3)];
        } else if (li < 14 && wv < 3){
            int sm = (wv==0)?s0:(wv==1)?s1:s2;
            gps_p = ((sm>>8)==0 ? gps0 : (sm>>8)==1 ? gps1 : gps2) + (size_t)(sm&255)*(TT*2);
            gpb[0][wv][li-12] = gps_p[li-12];
            gp_cur = gps_p[2 + (li-12)];
        } else if (li == 14 && wv < 3){
            int sm = (wv==0)?s0:(wv==1)?s1:s2;
            grid_p = ((sm>>8)==0 ? grid0 : (sm>>8)==1 ? grid1 : grid2) + (size_t)(sm&255)*TT;
            ring_s[wv][2] = grid_p[2];
            gd_cur = grid_p[3];
        }
    } else {
        if (nev_q > 0) next_t = ev_t_s[q][0];
    }
    __syncthreads();

#define STEP(T, P, P1)                                                                          \
{                                                                                               \
    f16x8 av[8];                                                                                \
    {                                                                                           \
        const f16* Arow = &A_s[P][lane & 3][q << 3];                                            \
        _Pragma("unroll")                                                                       \
        for (int ks = 0; ks < 8; ++ks)                                                          \
            av[ks] = *reinterpret_cast<const f16x8*>(Arow + ks*32);                             \
    }                                                                                           \
    const float gp0 = gpb[P][qc][0], gp1 = gpb[P][qc][1];                                       \
    if (q == 3){                                                                                \
        if (li < 12){                                                                           \
            f16x4 xd; xd[0]=(f16)ev_cur[0]; xd[1]=(f16)ev_cur[1];                               \
            xd[2]=(f16)ev_cur[2]; xd[3]=(f16)ev_cur[3];                                         \
            *reinterpret_cast<f16x4*>(&A_s[P1][em][xoff]) = xd;                                 \
            int idxn = ring_s[em][((T)+2) & 7];                                                 \
            f32x4 z = {0.f,0.f,0.f,0.f};                                                        \
            ev_cur = (idxn == 0) ? z : E4[(size_t)idxn*32 + (wv<<2) + (li&3)];                  \
        } else if (li < 14 && wv < 3){                                                          \
            gpb[P1][wv][li-12] = gp_cur;                                                        \
            int tn = (T)+2; if (tn > TT-1) tn = TT-1;                                           \
            gp_cur = gps_p[(size_t)tn*2 + (li-12)];                                             \
        } else if (li == 14 && wv < 3){                                                         \
            ring_s[wv][((T)+3) & 7] = gd_cur;                                                   \
            int tn = (T)+4; if (tn > TT-1) tn = TT-1;                                           \
            gd_cur = grid_p[tn];                                                                \
        }                                                                                       \
    }                                                                                           \
    f32x4 acI = {0.f,0.f,0.f,0.f}, acF = acI, acG = acI, acO = acI;                             \
    _Pragma("unroll")                                                                           \
    for (int ks = 0; ks < 8; ++ks){                                                             \
        acI = MF(av[ks], wI[ks], acI);                                                          \
        acF = MF(av[ks], wF[ks], acF);                                                          \
        acG = MF(av[ks], wG[ks], acG);                                                          \
        acO = MF(av[ks], wO[ks], acO);                                                          \
    }                                                                                           \
    if (q < 3){                                                                                 \
        float gI = ((q==0)?acI[0]:(q==1)?acI[1]:acI[2]) + bI_r + gp0*wgi0 + gp1*wgi1;           \
        float gF = ((q==0)?acF[0]:(q==1)?acF[1]:acF[2]) + bF_r + gp0*wgf0 + gp1*wgf1;           \
        float gG = ((q==0)?acG[0]:(q==1)?acG[1]:acG[2]) + bG_r + gp0*wgg0 + gp1*wgg1;           \
        float gO = ((q==0)?acO[0]:(q==1)?acO[1]:acO[2]) + bO_r + gp0*wgo0 + gp1*wgo1;           \
        if ((T) < len_q){                                                                       \
            float si = sigm(gI), sf = sigm(gF), so = sigm(gO);                                  \
            float tg = tanh_f(gG);                                                              \
            creg = sf * creg + si * tg;                                                         \
            hreg = so * tanh_f(creg);                                                           \
            while ((T) == next_t){                                                              \
                stash[(size_t)ev_sl_s[q][evp]*HH + u] = hreg;                                   \
                ++evp;                                                                          \
                next_t = (evp < nev_q) ? ev_t_s[q][evp] : (1<<30);                              \
            }                                                                                   \
        }                                                                                       \
        A_s[P1][q][128 + u] = (f16)hreg;                                                        \
    }                                                                                           \
    asm volatile("s_waitcnt lgkmcnt(0)" ::: "memory");                                          \
    __builtin_amdgcn_s_barrier();                                                               \
}

    int t = 0;
    for (; t + 1 < maxlen; t += 2){
        STEP(t,   0, 1);
        STEP(t+1, 1, 0);
    }
    if (t < maxlen){
        STEP(t, 0, 1);
    }
#undef STEP
}

// ---------------- fsim applied in-place on the stash (fp32, LDS-staged transposed weights) ----------------
__global__ void fsim_kernel(float* __restrict__ stash, const float* __restrict__ WT,
                            const float* __restrict__ bi, const float* __restrict__ bc, const float* __restrict__ bo,
                            const int* __restrict__ sub_ta, const int* __restrict__ sub_tf,
                            const int* __restrict__ sub_a, const int* __restrict__ sub_f,
                            const int* __restrict__ len_t, const int* __restrict__ len_a, const int* __restrict__ len_f)
{
    __shared__ float h_s[64][HH];
    __shared__ float w_s[3][32][HH];
    const int tid = threadIdx.x;
    const int base = blockIdx.x * 64;

    for (int i = tid; i < 64*HH; i += 256){
        int v = i >> 7, k = i & 127;
        int row = base + v;
        bool valid = true;
        if (row < 10240){
            int g = row / 2560, rr = row % 2560, b = rr / 10;
            int sub, len;
            if (g == 0){ sub = sub_ta[rr]; len = len_t[b]; }
            else if (g == 1){ sub = sub_tf[rr]; len = len_t[b]; }
            else if (g == 2){ sub = sub_a[rr]; len = len_a[b]; }
            else { sub = sub_f[rr]; len = len_f[b]; }
            valid = (sub - 1) < len;    // y is zero past length
        }
        h_s[v][k] = valid ? stash[(size_t)row * HH + k] : 0.f;
    }
    __syncthreads();

    const int uu = tid & 127;
    const int vb = (tid >> 7) << 5;
    float aI[32], aC[32], aO[32];
    #pragma unroll
    for (int v = 0; v < 32; ++v){ aI[v]=0.f; aC[v]=0.f; aO[v]=0.f; }

    for (int kc = 0; kc < 4; ++kc){
        for (int i = tid; i < 3*32*HH; i += 256){
            int w = i >> 12, rem = i & 4095, kk = rem >> 7, u2 = rem & 127;
            w_s[w][kk][u2] = WT[(size_t)w*16384 + (size_t)(kc*32 + kk)*HH + u2];
        }
        __syncthreads();
        for (int kk = 0; kk < 32; ++kk){
            float wi = w_s[0][kk][uu], wc = w_s[1][kk][uu], wo = w_s[2][kk][uu];
            #pragma unroll
            for (int v = 0; v < 32; ++v){
                float h = h_s[vb + v][kc*32 + kk];
                aI[v] = fmaf(h, wi, aI[v]);
                aC[v] = fmaf(h, wc, aC[v]);
                aO[v] = fmaf(h, wo, aO[v]);
            }
        }
        __syncthreads();
    }
    float BI = bi[uu], BC = bc[uu], BO = bo[uu];
    #pragma unroll
    for (int v = 0; v < 32; ++v){
        float C   = sigm(aI[v] + BI) * tanh_f(aC[v] + BC);
        float out = sigm(aO[v] + BO) * tanh_f(C) + h_s[vb + v][uu];
        stash[(size_t)(base + vb + v) * HH + uu] = out;
    }
}

// ---------------- distances: out = exp(-||u - v||) ----------------
__global__ void dist_kernel(const float* __restrict__ fs, float* __restrict__ out)
{
    int gid = blockIdx.x * 256 + threadIdx.x;
    int pair = gid >> 6, ln = gid & 63;
    if (pair >= 5632) return;
    int ia, ib;
    if (pair < 256){ ia = 10240 + pair; ib = 10240 + 256 + pair; }
    else if (pair < 512){ int j = pair - 256; ia = 10240 + j; ib = 10240 + 512 + j; }
    else if (pair < 3072){ int j = pair - 512; ia = j; ib = 5120 + j; }
    else { int j = pair - 3072; ia = 2560 + j; ib = 7680 + j; }
    float d = 0.f;
    #pragma unroll
    for (int k = 0; k < 2; ++k){
        int kk = ln + k*64;
        float df = fs[(size_t)ia*HH + kk] - fs[(size_t)ib*HH + kk];
        d = fmaf(df, df, d);
    }
    #pragma unroll
    for (int off = 32; off > 0; off >>= 1) d += __shfl_xor(d, off);
    if (ln == 0) out[pair] = __expf(-sqrtf(d));
}

extern "C" void kernel_launch(void* const* d_in, const int* in_sizes, int n_in,
                              void* d_out, int out_size, void* d_ws, size_t ws_size,
                              hipStream_t stream)
{
    (void)in_sizes; (void)n_in; (void)out_size; (void)ws_size;
    const float* traj_gps = (const float*)d_in[0];
    const int*   traj_grid = (const int*)d_in[2];
    const int*   traj_len = (const int*)d_in[4];
    const int*   sub_ta = (const int*)d_in[5];
    const int*   sub_tf = (const int*)d_in[6];
    const float* anc_gps = (const float*)d_in[7];
    const int*   anc_grid = (const int*)d_in[9];
    const int*   anc_len = (const int*)d_in[11];
    const int*   sub_a = (const int*)d_in[12];
    const float* far_gps = (const float*)d_in[13];
    const int*   far_grid = (const int*)d_in[15];
    const int*   far_len = (const int*)d_in[17];
    const int*   sub_f = (const int*)d_in[18];
    const float* E    = (const float*)d_in[19];
    const float* W_ih = (const float*)d_in[20];
    const float* W_hh = (const float*)d_in[21];
    const float* b_ih = (const float*)d_in[22];
    const float* b_hh = (const float*)d_in[23];
    const float* Wi = (const float*)d_in[24];
    const float* bi = (const float*)d_in[25];
    const float* Wc = (const float*)d_in[26];
    const float* bc = (const float*)d_in[27];
    const float* Wo = (const float*)d_in[28];
    const float* bo = (const float*)d_in[29];

    char* p = (char*)d_ws;
    f16* Wpack   = (f16*)p;   p += (size_t)512*256*2;
    float* Wg    = (float*)p; p += 1024*4;
    float* bsum  = (float*)p; p += 512*4;
    float* WT    = (float*)p; p += (size_t)3*128*128*4;
    int* order   = (int*)p;   p += 768*4;
    int* slen    = (int*)p;   p += 768*4;
    int* ev_t    = (int*)p;   p += 768*NEV*4;
    int* ev_slot = (int*)p;   p += 768*NEV*4;
    int* nev     = (int*)p;   p += 768*4;
    float* stash = (float*)p; p += (size_t)11008*128*4;   // also reused as fsim output

    pack_kernel<<<576, 256, 0, stream>>>(W_ih, W_hh, b_ih, b_hh, Wi, Wc, Wo, Wpack, Wg, bsum, WT);
    sched_kernel<<<1, 768, 0, stream>>>(traj_len, anc_len, far_len, sub_ta, sub_tf, sub_a, sub_f,
                                        order, slen, ev_t, ev_slot, nev);
    lstm_kernel<<<256, 512, 0, stream>>>(traj_gps, anc_gps, far_gps, traj_grid, anc_grid, far_grid,
                                         E, Wpack, Wg, bsum, order, slen, ev_t, ev_slot, nev, stash);
    fsim_kernel<<<172, 256, 0, stream>>>(stash, WT, bi, bc, bo, sub_ta, sub_tf, sub_a, sub_f,
                                         traj_len, anc_len, far_len);
    dist_kernel<<<1408, 256, 0, stream>>>(stash, (float*)d_out);
}

// Round 4
// 1155.145 us; speedup vs baseline: 1.2679x; 1.2679x over previous
//
#include <hip/hip_runtime.h>
#include <math.h>

typedef _Float16 f16;
typedef _Float16 f16x8 __attribute__((ext_vector_type(8)));
typedef _Float16 f16x4 __attribute__((ext_vector_type(4)));
typedef float f32x4 __attribute__((ext_vector_type(4)));

#define TT 1024
#define HH 128
#define SROWH 144    // halves per A_s row (h-only): 72 dwords -> 8-bank shift/row, 2 addrs/bank on reads (free)
#define XGSTR 520    // halves per xg_lds stream row (16B aligned rows)
#define NEV 24

__device__ __forceinline__ float sigm(float x){ return 1.f/(1.f + __expf(-x)); }
__device__ __forceinline__ float tanh_f(float x){
    float ax = fabsf(x);
    float e = __expf(-2.f*ax);
    float r = (1.f - e)/(1.f + e);
    return (x < 0.f) ? -r : r;
}

#define MF(a,b,c) __builtin_amdgcn_mfma_f32_16x16x32_f16((a),(b),(c),0,0,0)

// ---------------- prep: pack W_hh (f16), W_ih K-part reordered [o=u*4+g][k] (f16), gps cols, bias sum, fsim W^T ----------------
__global__ void pack_kernel(const float* __restrict__ W_ih, const float* __restrict__ W_hh,
                            const float* __restrict__ b_ih, const float* __restrict__ b_hh,
                            const float* __restrict__ Wi, const float* __restrict__ Wc, const float* __restrict__ Wo,
                            f16* __restrict__ Whh_p, f16* __restrict__ Wih_p, float* __restrict__ Wg,
                            float* __restrict__ bsum, float* __restrict__ WT)
{
    int idx = blockIdx.x*256 + threadIdx.x;
    if (idx < 512*128){
        Whh_p[idx] = (f16)W_hh[idx];                  // rows j = g*128+u, k<128
        int o = idx >> 7, k = idx & 127;
        int u = o >> 2, g = o & 3;
        Wih_p[idx] = (f16)W_ih[(g*128 + u)*130 + k];  // [o][k]
    }
    if (idx < 1024){
        int j = idx >> 1, c = idx & 1;
        Wg[idx] = W_ih[j*130 + 128 + c];
    }
    if (idx < 512) bsum[idx] = b_ih[idx] + b_hh[idx];
    if (idx < 3*128*128){
        int w = idx >> 14, rem = idx & 16383, k = rem >> 7, u = rem & 127;
        const float* W = (w==0) ? Wi : (w==1) ? Wc : Wo;
        WT[idx] = W[u*128 + k];   // WT[w][k][u] = W[u][k]
    }
}

// ---------------- precompute xgT[word][o = u*4+g] = (E0[word] . W_ih[:, :128]^T), f16 ----------------
__global__ void xg_gemm(const float* __restrict__ E, const f16* __restrict__ Wih_p,
                        f16* __restrict__ xgT, int NW)
{
    const int w = threadIdx.x >> 6, lane = threadIdx.x & 63;
    const int li = lane & 15, q = lane >> 4;
    const int word = blockIdx.x*64 + w*16 + li;

    f16x8 a[4];
    const bool valid = (word > 0) && (word < NW);
    #pragma unroll
    for (int ks = 0; ks < 4; ++ks){
        f32x4 v0 = {0.f,0.f,0.f,0.f}, v1 = v0;
        if (valid){
            const f32x4* Er = (const f32x4*)(E + (size_t)word*HH);
            v0 = Er[ks*8 + q*2];
            v1 = Er[ks*8 + q*2 + 1];
        }
        f16x8 t;
        t[0]=(f16)v0[0]; t[1]=(f16)v0[1]; t[2]=(f16)v0[2]; t[3]=(f16)v0[3];
        t[4]=(f16)v1[0]; t[5]=(f16)v1[1]; t[6]=(f16)v1[2]; t[7]=(f16)v1[3];
        a[ks] = t;
    }
    const int wbase = blockIdx.x*64 + w*16 + q*4;
    for (int nt = 0; nt < 32; ++nt){
        f32x4 acc = {0.f,0.f,0.f,0.f};
        #pragma unroll
        for (int ks = 0; ks < 4; ++ks){
            f16x8 b = *reinterpret_cast<const f16x8*>(Wih_p + (nt*16 + li)*128 + ks*32 + q*8);
            acc = MF(a[ks], b, acc);
        }
        #pragma unroll
        for (int r = 0; r < 4; ++r){
            int wr = wbase + r;
            if (wr < NW) xgT[(size_t)wr*512 + nt*16 + li] = (f16)acc[r];
        }
    }
}

// ---------------- prep: length sort + per-stream sorted event lists ----------------
__device__ __forceinline__ void add_ev(int* et, int* es, int& n, int t, int slot, int len){
    if (t < 0 || t >= len) return;
    int p = n++;
    while (p > 0 && et[p-1] > t){ et[p] = et[p-1]; es[p] = es[p-1]; --p; }
    et[p] = t; es[p] = slot;
}

__global__ void sched_kernel(const int* __restrict__ len_t, const int* __restrict__ len_a, const int* __restrict__ len_f,
                             const int* __restrict__ sub_ta, const int* __restrict__ sub_tf,
                             const int* __restrict__ sub_a, const int* __restrict__ sub_f,
                             int* __restrict__ order, int* __restrict__ slen,
                             int* __restrict__ ev_t, int* __restrict__ ev_slot, int* __restrict__ nev)
{
    __shared__ int L[768];
    int s = threadIdx.x;              // 0..767, stream id = e*256 + b
    int e = s >> 8, b = s & 255;
    int len = (e==0) ? len_t[b] : (e==1) ? len_a[b] : len_f[b];
    L[s] = len;
    __syncthreads();
    int rank = 0;
    for (int i = 0; i < 768; ++i){
        int li = L[i];
        rank += (li > len) || (li == len && i < s);
    }
    order[rank] = s;                  // descending by length, bijective
    slen[s] = len;

    int et[NEV], es[NEV]; int n = 0;
    if (e == 0){
        for (int r = 0; r < 10; ++r){
            add_ev(et, es, n, sub_ta[b*10+r]-1, b*10+r,        len);
            add_ev(et, es, n, sub_tf[b*10+r]-1, 2560 + b*10+r, len);
        }
    } else if (e == 1){
        for (int r = 0; r < 10; ++r) add_ev(et, es, n, sub_a[b*10+r]-1, 5120 + b*10+r, len);
    } else {
        for (int r = 0; r < 10; ++r) add_ev(et, es, n, sub_f[b*10+r]-1, 7680 + b*10+r, len);
    }
    add_ev(et, es, n, len-1, 10240 + s, len);   // final hidden state
    nev[s] = n;
    for (int i = 0; i < n; ++i){ ev_t[s*NEV+i] = et[i]; ev_slot[s*NEV+i] = es[i]; }
}

// ---------------- main LSTM: 12 waves = 8 compute (K=128 h-MFMA + nonlin) + 3 xg-staging + 1 gps/ring ----------------
__launch_bounds__(768, 3)
__global__ void lstm_kernel(const float* __restrict__ gps0, const float* __restrict__ gps1, const float* __restrict__ gps2,
                            const int* __restrict__ grid0, const int* __restrict__ grid1, const int* __restrict__ grid2,
                            const f16* __restrict__ xgT,
                            const f16* __restrict__ Whh_p, const float* __restrict__ Wg, const float* __restrict__ bsum,
                            const int* __restrict__ order, const int* __restrict__ slen,
                            const int* __restrict__ ev_t, const int* __restrict__ ev_slot, const int* __restrict__ nev,
                            float* __restrict__ stash)
{
    __shared__ f16   A_s[2][4][SROWH];     // h per stream (rows 0..2), row 3 = zero; double-buffered
    __shared__ f16   xg_lds[2][3][XGSTR];  // precomputed x-gate row per stream, double-buffered
    __shared__ float gpb[2][3][2];         // gps pair per stream (fp32), double-buffered
    __shared__ int   ring_s[3][8];         // grid-index ring
    __shared__ int   ev_t_s[3][NEV];
    __shared__ int   ev_sl_s[3][NEV];

    const int tid  = threadIdx.x;
    const int lane = tid & 63;
    const int wv   = tid >> 6;          // 0..11
    const int q    = lane >> 4;         // lane quarter (k-group for frags, stream for D/nonlin)
    const int li   = lane & 15;
    const int u    = ((wv & 7) << 4) + li;
    const int qc   = (q < 3) ? q : 2;
    const int bi   = blockIdx.x;

    const int s0 = order[bi], s1 = order[bi+256], s2 = order[bi+512];
    const int l0 = slen[s0], l1 = slen[s1], l2 = slen[s2];
    int maxlen = l0 > l1 ? l0 : l1; if (l2 > maxlen) maxlen = l2;

    // ---- init LDS ----
    for (int i = tid; i < 2*4*SROWH; i += 768) (&A_s[0][0][0])[i] = (f16)0.f;
    if (tid < 72){
        int m = tid / NEV, i = tid % NEV;
        int sm = (m==0) ? s0 : (m==1) ? s1 : s2;
        ev_t_s[m][i]  = ev_t[sm*NEV + i];
        ev_sl_s[m][i] = ev_slot[sm*NEV + i];
    }

    // ---- compute-wave persistent state ----
    f16x8 wI[4], wF[4], wG[4], wO[4];
    float wgi0=0,wgi1=0,wgf0=0,wgf1=0,wgg0=0,wgg1=0,wgo0=0,wgo1=0;
    float bI_r=0.f, bF_r=0.f, bG_r=0.f, bO_r=0.f, creg=0.f, hreg=0.f;
    int len_q=0, nev_q=0, evp=0, next_t=1<<30;

    // staging-wave persistent state
    f16x8 xga = {};
    float gp_cur = 0.f;
    int   gd_cur = 0;
    const float* gps_p = nullptr;
    const int*   grid_p = nullptr;

    if (wv < 8){
        const int kg = q << 3;
        #pragma unroll
        for (int ks = 0; ks < 4; ++ks){
            const int koff = ks*32 + kg;
            wI[ks] = *reinterpret_cast<const f16x8*>(Whh_p + (size_t)(  0 + u) * 128 + koff);
            wF[ks] = *reinterpret_cast<const f16x8*>(Whh_p + (size_t)(128 + u) * 128 + koff);
            wG[ks] = *reinterpret_cast<const f16x8*>(Whh_p + (size_t)(256 + u) * 128 + koff);
            wO[ks] = *reinterpret_cast<const f16x8*>(Whh_p + (size_t)(384 + u) * 128 + koff);
        }
        wgi0 = Wg[u*2];        wgi1 = Wg[u*2+1];
        wgf0 = Wg[(128+u)*2];  wgf1 = Wg[(128+u)*2+1];
        wgg0 = Wg[(256+u)*2];  wgg1 = Wg[(256+u)*2+1];
        wgo0 = Wg[(384+u)*2];  wgo1 = Wg[(384+u)*2+1];
        bI_r = bsum[u]; bF_r = bsum[128+u]; bG_r = bsum[256+u]; bO_r = bsum[384+u];
        if (q < 3){
            int sq = (q==0)?s0:(q==1)?s1:s2;
            len_q = (q==0)?l0:(q==1)?l1:l2;
            nev_q = nev[sq];
        }
    }

    __syncthreads();   // LDS zero-init + ev lists visible

    // ---- prologue ----
    if (wv >= 8 && wv < 11){
        const int sm = wv - 8;
        const int ss = (sm==0)?s0:(sm==1)?s1:s2;
        grid_p = ((ss>>8)==0 ? grid0 : (ss>>8)==1 ? grid1 : grid2) + (size_t)(ss&255)*TT;
        int i0 = grid_p[0], i1 = grid_p[1];
        *reinterpret_cast<f16x8*>(&xg_lds[0][sm][lane<<3]) =
            *reinterpret_cast<const f16x8*>(xgT + (i0<<9) + (lane<<3));
        xga = *reinterpret_cast<const f16x8*>(xgT + (i1<<9) + (lane<<3));
    } else if (wv == 11){
        if (lane < 6){
            int sm = lane >> 1, c = lane & 1;
            int ss = (sm==0)?s0:(sm==1)?s1:s2;
            gps_p = ((ss>>8)==0 ? gps0 : (ss>>8)==1 ? gps1 : gps2) + (size_t)(ss&255)*(TT*2);
            gpb[0][sm][c] = gps_p[c];
            gp_cur = gps_p[2 + c];
        } else if (lane >= 8 && lane < 11){
            int sm = lane - 8;
            int ss = (sm==0)?s0:(sm==1)?s1:s2;
            grid_p = ((ss>>8)==0 ? grid0 : (ss>>8)==1 ? grid1 : grid2) + (size_t)(ss&255)*TT;
            ring_s[sm][2] = grid_p[2];
            gd_cur = grid_p[3];
        }
    } else if (q < 3){
        if (nev_q > 0) next_t = ev_t_s[q][0];
    }
    __syncthreads();

#define STEP(T, P, P1)                                                                          \
{                                                                                               \
    if (wv < 8){                                                                                \
        f16x8 av[4];                                                                            \
        {                                                                                       \
            const f16* Arow = &A_s[P][li >> 2][q << 3];                                         \
            _Pragma("unroll")                                                                   \
            for (int ks = 0; ks < 4; ++ks)                                                      \
                av[ks] = *reinterpret_cast<const f16x8*>(Arow + ks*32);                         \
        }                                                                                       \
        f16x4 xgv = *reinterpret_cast<const f16x4*>(&xg_lds[P][qc][u << 2]);                    \
        const float gp0 = gpb[P][qc][0], gp1 = gpb[P][qc][1];                                   \
        f32x4 acI = {0.f,0.f,0.f,0.f}, acF = acI, acG = acI, acO = acI;                         \
        __builtin_amdgcn_s_setprio(1);                                                          \
        _Pragma("unroll")                                                                       \
        for (int ks = 0; ks < 4; ++ks){                                                         \
            acI = MF(av[ks], wI[ks], acI);                                                      \
            acF = MF(av[ks], wF[ks], acF);                                                      \
            acG = MF(av[ks], wG[ks], acG);                                                      \
            acO = MF(av[ks], wO[ks], acO);                                                      \
        }                                                                                       \
        __builtin_amdgcn_s_setprio(0);                                                          \
        if (q < 3){                                                                             \
            float gI = acI[0] + (float)xgv[0] + bI_r + gp0*wgi0 + gp1*wgi1;                     \
            float gF = acF[0] + (float)xgv[1] + bF_r + gp0*wgf0 + gp1*wgf1;                     \
            float gG = acG[0] + (float)xgv[2] + bG_r + gp0*wgg0 + gp1*wgg1;                     \
            float gO = acO[0] + (float)xgv[3] + bO_r + gp0*wgo0 + gp1*wgo1;                     \
            if ((T) < len_q){                                                                   \
                float si = sigm(gI), sf = sigm(gF), so = sigm(gO);                              \
                float tg = tanh_f(gG);                                                          \
                creg = sf * creg + si * tg;                                                     \
                hreg = so * tanh_f(creg);                                                       \
                while ((T) == next_t){                                                          \
                    stash[ev_sl_s[q][evp]*HH + u] = hreg;                                       \
                    ++evp;                                                                      \
                    next_t = (evp < nev_q) ? ev_t_s[q][evp] : (1<<30);                          \
                }                                                                               \
            }                                                                                   \
            A_s[P1][q][u] = (f16)hreg;                                                          \
        }                                                                                       \
    } else if (wv < 11){                                                                        \
        const int sm = wv - 8;                                                                  \
        *reinterpret_cast<f16x8*>(&xg_lds[P1][sm][lane << 3]) = xga;                            \
        int idxn = ring_s[sm][((T)+2) & 7];                                                     \
        xga = *reinterpret_cast<const f16x8*>(xgT + (idxn << 9) + (lane << 3));                 \
    } else {                                                                                    \
        if (lane < 6){                                                                          \
            int sm = lane >> 1, c = lane & 1;                                                   \
            gpb[P1][sm][c] = gp_cur;                                                            \
            int tn = (T)+2; if (tn > TT-1) tn = TT-1;                                           \
            gp_cur = gps_p[(size_t)tn*2 + c];                                                   \
        } else if (lane >= 8 && lane < 11){                                                     \
            int sm = lane - 8;                                                                  \
            ring_s[sm][((T)+3) & 7] = gd_cur;                                                   \
            int tn = (T)+4; if (tn > TT-1) tn = TT-1;                                           \
            gd_cur = grid_p[tn];                                                                \
        }                                                                                       \
    }                                                                                           \
    asm volatile("s_waitcnt lgkmcnt(0)" ::: "memory");                                          \
    __builtin_amdgcn_s_barrier();                                                               \
    asm volatile("" ::: "memory");                                                              \
}

    int t = 0;
    for (; t + 1 < maxlen; t += 2){
        STEP(t,   0, 1);
        STEP(t+1, 1, 0);
    }
    if (t < maxlen){
        STEP(t, 0, 1);
    }
#undef STEP
}

// ---------------- fsim applied in-place on the stash (fp32, LDS-staged transposed weights) ----------------
__global__ void fsim_kernel(float* __restrict__ stash, const float* __restrict__ WT,
                            const float* __restrict__ bi, const float* __restrict__ bc, const float* __restrict__ bo,
                            const int* __restrict__ sub_ta, const int* __restrict__ sub_tf,
                            const int* __restrict__ sub_a, const int* __restrict__ sub_f,
                            const int* __restrict__ len_t, const int* __restrict__ len_a, const int* __restrict__ len_f)
{
    __shared__ float h_s[64][HH];
    __shared__ float w_s[3][32][HH];
    const int tid = threadIdx.x;
    const int base = blockIdx.x * 64;

    for (int i = tid; i < 64*HH; i += 256){
        int v = i >> 7, k = i & 127;
        int row = base + v;
        bool valid = true;
        if (row < 10240){
            int g = row / 2560, rr = row % 2560, b = rr / 10;
            int sub, len;
            if (g == 0){ sub = sub_ta[rr]; len = len_t[b]; }
            else if (g == 1){ sub = sub_tf[rr]; len = len_t[b]; }
            else if (g == 2){ sub = sub_a[rr]; len = len_a[b]; }
            else { sub = sub_f[rr]; len = len_f[b]; }
            valid = (sub - 1) < len;    // y is zero past length
        }
        h_s[v][k] = valid ? stash[(size_t)row * HH + k] : 0.f;
    }
    __syncthreads();

    const int uu = tid & 127;
    const int vb = (tid >> 7) << 5;
    float aI[32], aC[32], aO[32];
    #pragma unroll
    for (int v = 0; v < 32; ++v){ aI[v]=0.f; aC[v]=0.f; aO[v]=0.f; }

    for (int kc = 0; kc < 4; ++kc){
        for (int i = tid; i < 3*32*HH; i += 256){
            int w = i >> 12, rem = i & 4095, kk = rem >> 7, u2 = rem & 127;
            w_s[w][kk][u2] = WT[(size_t)w*16384 + (size_t)(kc*32 + kk)*HH + u2];
        }
        __syncthreads();
        for (int kk = 0; kk < 32; ++kk){
            float wi = w_s[0][kk][uu], wc = w_s[1][kk][uu], wo = w_s[2][kk][uu];
            #pragma unroll
            for (int v = 0; v < 32; ++v){
                float h = h_s[vb + v][kc*32 + kk];
                aI[v] = fmaf(h, wi, aI[v]);
                aC[v] = fmaf(h, wc, aC[v]);
                aO[v] = fmaf(h, wo, aO[v]);
            }
        }
        __syncthreads();
    }
    float BI = bi[uu], BC = bc[uu], BO = bo[uu];
    #pragma unroll
    for (int v = 0; v < 32; ++v){
        float C   = sigm(aI[v] + BI) * tanh_f(aC[v] + BC);
        float out = sigm(aO[v] + BO) * tanh_f(C) + h_s[vb + v][uu];
        stash[(size_t)(base + vb + v) * HH + uu] = out;
    }
}

// ---------------- distances: out = exp(-||u - v||) ----------------
__global__ void dist_kernel(const float* __restrict__ fs, float* __restrict__ out)
{
    int gid = blockIdx.x * 256 + threadIdx.x;
    int pair = gid >> 6, ln = gid & 63;
    if (pair >= 5632) return;
    int ia, ib;
    if (pair < 256){ ia = 10240 + pair; ib = 10240 + 256 + pair; }
    else if (pair < 512){ int j = pair - 256; ia = 10240 + j; ib = 10240 + 512 + j; }
    else if (pair < 3072){ int j = pair - 512; ia = j; ib = 5120 + j; }
    else { int j = pair - 3072; ia = 2560 + j; ib = 7680 + j; }
    float d = 0.f;
    #pragma unroll
    for (int k = 0; k < 2; ++k){
        int kk = ln + k*64;
        float df = fs[(size_t)ia*HH + kk] - fs[(size_t)ib*HH + kk];
        d = fmaf(df, df, d);
    }
    #pragma unroll
    for (int off = 32; off > 0; off >>= 1) d += __shfl_xor(d, off);
    if (ln == 0) out[pair] = __expf(-sqrtf(d));
}

extern "C" void kernel_launch(void* const* d_in, const int* in_sizes, int n_in,
                              void* d_out, int out_size, void* d_ws, size_t ws_size,
                              hipStream_t stream)
{
    (void)n_in; (void)out_size; (void)ws_size;
    const float* traj_gps = (const float*)d_in[0];
    const int*   traj_grid = (const int*)d_in[2];
    const int*   traj_len = (const int*)d_in[4];
    const int*   sub_ta = (const int*)d_in[5];
    const int*   sub_tf = (const int*)d_in[6];
    const float* anc_gps = (const float*)d_in[7];
    const int*   anc_grid = (const int*)d_in[9];
    const int*   anc_len = (const int*)d_in[11];
    const int*   sub_a = (const int*)d_in[12];
    const float* far_gps = (const float*)d_in[13];
    const int*   far_grid = (const int*)d_in[15];
    const int*   far_len = (const int*)d_in[17];
    const int*   sub_f = (const int*)d_in[18];
    const float* E    = (const float*)d_in[19];
    const float* W_ih = (const float*)d_in[20];
    const float* W_hh = (const float*)d_in[21];
    const float* b_ih = (const float*)d_in[22];
    const float* b_hh = (const float*)d_in[23];
    const float* Wi = (const float*)d_in[24];
    const float* bi = (const float*)d_in[25];
    const float* Wc = (const float*)d_in[26];
    const float* bc = (const float*)d_in[27];
    const float* Wo = (const float*)d_in[28];
    const float* bo = (const float*)d_in[29];

    const int NW_rt = in_sizes[19] / HH;   // 50000

    char* p = (char*)d_ws;
    f16* Whh_p   = (f16*)p;   p += (size_t)512*128*2;
    f16* Wih_p   = (f16*)p;   p += (size_t)512*128*2;
    float* Wg    = (float*)p; p += 1024*4;
    float* bsum  = (float*)p; p += 512*4;
    float* WT    = (float*)p; p += (size_t)3*128*128*4;
    int* order   = (int*)p;   p += 768*4;
    int* slen    = (int*)p;   p += 768*4;
    int* ev_t    = (int*)p;   p += 768*NEV*4;
    int* ev_slot = (int*)p;   p += 768*NEV*4;
    int* nev     = (int*)p;   p += 768*4;
    float* stash = (float*)p; p += (size_t)11008*128*4;
    f16* xgT     = (f16*)p;   p += (size_t)NW_rt*512*2;

    pack_kernel<<<576, 256, 0, stream>>>(W_ih, W_hh, b_ih, b_hh, Wi, Wc, Wo,
                                         Whh_p, Wih_p, Wg, bsum, WT);
    xg_gemm<<<(NW_rt + 63)/64, 256, 0, stream>>>(E, Wih_p, xgT, NW_rt);
    sched_kernel<<<1, 768, 0, stream>>>(traj_len, anc_len, far_len, sub_ta, sub_tf, sub_a, sub_f,
                                        order, slen, ev_t, ev_slot, nev);
    lstm_kernel<<<256, 768, 0, stream>>>(traj_gps, anc_gps, far_gps, traj_grid, anc_grid, far_grid,
                                         xgT, Whh_p, Wg, bsum, order, slen, ev_t, ev_slot, nev, stash);
    fsim_kernel<<<172, 256, 0, stream>>>(stash, WT, bi, bc, bo, sub_ta, sub_tf, sub_a, sub_f,
                                         traj_len, anc_len, far_len);
    dist_kernel<<<1408, 256, 0, stream>>>(stash, (float*)d_out);
}